// Round 8
// baseline (306.545 us; speedup 1.0000x reference)
//
#include <hip/hip_runtime.h>
#include <float.h>
#include <math.h>

#define N 512
#define E 16384
#define D 1280
#define LMDIM 1024
#define NFDIM 256
#define M 64
#define MAXDEG 512   // in-degree cap; Poisson(32) for this fixed input, tail << 512

typedef __attribute__((ext_vector_type(8))) short s8v;   // 8 bf16 operand (4 VGPRs)
typedef __attribute__((ext_vector_type(4))) float f4v;   // 4 fp32 acc

// ---------- bf16 helpers ----------
__device__ __forceinline__ unsigned short f2bf(float x) {
  unsigned u = __float_as_uint(x);
  unsigned r = (u + 0x7fffu + ((u >> 16) & 1u)) >> 16;   // RNE
  return (unsigned short)r;
}
__device__ __forceinline__ float bf2f(unsigned short h) {
  return __uint_as_float(((unsigned)h) << 16);
}

// h[i][j] = j < 1024 ? lm[0, i+1, j] : nf[i, j-1024]
__device__ __forceinline__ float h_val(const float* __restrict__ lm,
                                       const float* __restrict__ nf,
                                       int i, int j) {
  return (j < LMDIM) ? lm[(i + 1) * LMDIM + j] : nf[i * NFDIM + (j - LMDIM)];
}
__device__ __forceinline__ float4 h_vec4(const float* __restrict__ lm,
                                         const float* __restrict__ nf,
                                         int i, int t) {  // t = col/4, 0..319
  return (t < 256) ? *(const float4*)&lm[(size_t)(i + 1) * LMDIM + t * 4]
                   : *(const float4*)&nf[(size_t)i * NFDIM + (t - 256) * 4];
}

// =================== FAST PATH ===================

// ---- prep: blocks 0..1599 = W-split tiles; 1600..2111 = neigh (1 node each) ----
union __align__(16) PrepSMem {
  float T[32][33];                 // convw transpose tile (4224 B)
  struct {
    int   s_e[MAXDEG];             // matched edge ids
    int   s_src[MAXDEG];
    float s_w[MAXDEG];
    int   s_cnt;
  } ng;                            // 6148 B
};

__global__ __launch_bounds__(320) void prep_kernel(
    const float* __restrict__ lm, const float* __restrict__ nf,
    const float* __restrict__ ew, const int* __restrict__ src,
    const int* __restrict__ dst, const float* __restrict__ Wg,
    unsigned short* __restrict__ AHi, unsigned short* __restrict__ ALo,
    unsigned short* __restrict__ WtHi, unsigned short* __restrict__ WtLo,
    float* __restrict__ p) {
  __shared__ PrepSMem sm;
  int b = blockIdx.x;
  int t = threadIdx.x;

  if (b < 1600) {
    // ----- convw: Wt[n][k] = W[k][n], bf16 hi/lo split (256 active threads) -----
    if (t < 256) {
      int bx = b % 40, by = b / 40;        // bx: n-tile, by: k-tile
      int c = t & 31, r0 = t >> 5;
#pragma unroll
      for (int rr = 0; rr < 4; ++rr) {
        int r = r0 + rr * 8;
        sm.T[r][c] = Wg[(by * 32 + r) * D + bx * 32 + c];
      }
      __syncthreads();
#pragma unroll
      for (int rr = 0; rr < 4; ++rr) {
        int rn = r0 + rr * 8;
        float v = sm.T[c][rn];             // = Wg[by*32+c][bx*32+rn]
        unsigned short hi = f2bf(v);
        unsigned short lo = f2bf(v - bf2f(hi));
        size_t o = (size_t)(bx * 32 + rn) * D + by * 32 + c;
        WtHi[o] = hi;
        WtLo[o] = lo;
      }
    } else {
      __syncthreads();                     // match the barrier above
    }
  } else {
    // ----- neigh for node n: MLP-pipelined edge scan + batched max gather -----
    int n = b - 1600;                      // 0..511
    if (t == 0) {
      sm.ng.s_cnt = 0;
      p[n] = 0.0f;                         // gemm accumulates p with atomics
    }
    __syncthreads();
    // 1) edge scan: int4 loads, matches push edge id only (independent loads pipeline)
    const int4* dst4 = (const int4*)dst;
    for (int i = t; i < E / 4; i += 320) {
      int4 d4 = dst4[i];
      if (d4.x == n) { int pos = atomicAdd(&sm.ng.s_cnt, 1); if (pos < MAXDEG) sm.ng.s_e[pos] = 4 * i + 0; }
      if (d4.y == n) { int pos = atomicAdd(&sm.ng.s_cnt, 1); if (pos < MAXDEG) sm.ng.s_e[pos] = 4 * i + 1; }
      if (d4.z == n) { int pos = atomicAdd(&sm.ng.s_cnt, 1); if (pos < MAXDEG) sm.ng.s_e[pos] = 4 * i + 2; }
      if (d4.w == n) { int pos = atomicAdd(&sm.ng.s_cnt, 1); if (pos < MAXDEG) sm.ng.s_e[pos] = 4 * i + 3; }
    }
    __syncthreads();
    int cnt = min(sm.ng.s_cnt, MAXDEG);
    // 2) resolve src/weight for all matches in one parallel step (cnt < 320)
    if (t < cnt) {
      int e = sm.ng.s_e[t];
      sm.ng.s_src[t] = src[e];
      sm.ng.s_w[t] = ew[e];
    }
    __syncthreads();
    // 3) batched max: 8 independent row-gathers in flight per group
    float4 m = make_float4(-FLT_MAX, -FLT_MAX, -FLT_MAX, -FLT_MAX);
    int i = 0;
    for (; i + 8 <= cnt; i += 8) {
      float4 v[8];
      float wgt[8];
#pragma unroll
      for (int j = 0; j < 8; ++j) {
        int s = sm.ng.s_src[i + j];
        wgt[j] = sm.ng.s_w[i + j];
        v[j] = h_vec4(lm, nf, s, t);
      }
#pragma unroll
      for (int j = 0; j < 8; ++j) {
        m.x = fmaxf(m.x, v[j].x * wgt[j]);
        m.y = fmaxf(m.y, v[j].y * wgt[j]);
        m.z = fmaxf(m.z, v[j].z * wgt[j]);
        m.w = fmaxf(m.w, v[j].w * wgt[j]);
      }
    }
    for (; i < cnt; ++i) {
      int s = sm.ng.s_src[i];
      float wgt = sm.ng.s_w[i];
      float4 v = h_vec4(lm, nf, s, t);
      m.x = fmaxf(m.x, v.x * wgt);
      m.y = fmaxf(m.y, v.y * wgt);
      m.z = fmaxf(m.z, v.z * wgt);
      m.w = fmaxf(m.w, v.w * wgt);
    }
    bool has = (cnt > 0);
    float4 hv = h_vec4(lm, nf, n, t);
    float4 a;
    a.x = hv.x + (has ? m.x : 0.0f);
    a.y = hv.y + (has ? m.y : 0.0f);
    a.z = hv.z + (has ? m.z : 0.0f);
    a.w = hv.w + (has ? m.w : 0.0f);
    ushort4 hi, lo;
    hi.x = f2bf(a.x); lo.x = f2bf(a.x - bf2f(hi.x));
    hi.y = f2bf(a.y); lo.y = f2bf(a.y - bf2f(hi.y));
    hi.z = f2bf(a.z); lo.z = f2bf(a.z - bf2f(hi.z));
    hi.w = f2bf(a.w); lo.w = f2bf(a.w - bf2f(hi.w));
    size_t o = (size_t)n * D + t * 4;      // t*4 spans 0..1279 exactly
    *(ushort4*)&AHi[o] = hi;
    *(ushort4*)&ALo[o] = lo;
  }
}

// ---- MFMA GEMM: NO = A @ W_g + b_g + h ; fused p += NO @ W_d ----
// K-loop: LDS double-buffer + depth-2 register prefetch, ONE barrier per iter.
// Safety of the single barrier: each wave's MFMAs consume its ds_reads of
// LDS[buf] before the wave reaches the next barrier, so overwriting LDS[buf]
// two iterations later (after that barrier) cannot race the reads.
__global__ __launch_bounds__(256) void gemm_mfma_kernel(const unsigned short* __restrict__ AHi,
                                                        const unsigned short* __restrict__ ALo,
                                                        const unsigned short* __restrict__ WtHi,
                                                        const unsigned short* __restrict__ WtLo,
                                                        const float* __restrict__ bg,
                                                        const float* __restrict__ Wd,
                                                        const float* __restrict__ lm,
                                                        const float* __restrict__ nf,
                                                        float* __restrict__ NO,
                                                        float* __restrict__ p) {
  __shared__ __align__(16) short Ah[2][64][40];
  __shared__ __align__(16) short Al[2][64][40];
  __shared__ __align__(16) short Bh[2][64][40];
  __shared__ __align__(16) short Bl[2][64][40];

  int tid = threadIdx.x;
  int rowBase = blockIdx.y * 64;
  int colBase = blockIdx.x * 64;

  int sr = tid >> 2;                // staging row 0..63
  int sq = (tid & 3) << 3;          // staging k-offset in shorts (0,8,16,24)

  int w = tid >> 6;                 // wave 0..3 -> rows w*16..w*16+15
  int L = tid & 63;
  int q = L >> 4;                   // quad
  int c = L & 15;

  f4v acc[4];
#pragma unroll
  for (int i = 0; i < 4; ++i) acc[i] = (f4v){0.f, 0.f, 0.f, 0.f};

  const size_t aOff = (size_t)(rowBase + sr) * D + sq;
  const size_t bOff = (size_t)(colBase + sr) * D + sq;

  // depth-2 register prefetch (k0 = 0, 32)
  s8v va[2], vl[2], vb[2], vm[2];
#pragma unroll
  for (int j = 0; j < 2; ++j) {
    va[j] = *(const s8v*)&AHi[aOff + j * 32];
    vl[j] = *(const s8v*)&ALo[aOff + j * 32];
    vb[j] = *(const s8v*)&WtHi[bOff + j * 32];
    vm[j] = *(const s8v*)&WtLo[bOff + j * 32];
  }

  for (int it = 0; it < D / 32; ++it) {
    int buf = it & 1;
    // stage (waits only on loads issued 2 iters ago -> latency mostly hidden)
    *(s8v*)&Ah[buf][sr][sq] = va[buf];
    *(s8v*)&Al[buf][sr][sq] = vl[buf];
    *(s8v*)&Bh[buf][sr][sq] = vb[buf];
    *(s8v*)&Bl[buf][sr][sq] = vm[buf];
    // prefetch k0 + 64
    int kn = (it + 2) * 32;
    if (kn < D) {
      va[buf] = *(const s8v*)&AHi[aOff + kn];
      vl[buf] = *(const s8v*)&ALo[aOff + kn];
      vb[buf] = *(const s8v*)&WtHi[bOff + kn];
      vm[buf] = *(const s8v*)&WtLo[bOff + kn];
    }
    __syncthreads();

    s8v ah = *(const s8v*)&Ah[buf][w * 16 + c][q * 8];
    s8v al = *(const s8v*)&Al[buf][w * 16 + c][q * 8];
#pragma unroll
    for (int ct = 0; ct < 4; ++ct) {
      s8v bh = *(const s8v*)&Bh[buf][ct * 16 + c][q * 8];
      s8v bl = *(const s8v*)&Bl[buf][ct * 16 + c][q * 8];
      acc[ct] = __builtin_amdgcn_mfma_f32_16x16x32_bf16(ah, bh, acc[ct], 0, 0, 0);
      acc[ct] = __builtin_amdgcn_mfma_f32_16x16x32_bf16(al, bh, acc[ct], 0, 0, 0);
      acc[ct] = __builtin_amdgcn_mfma_f32_16x16x32_bf16(ah, bl, acc[ct], 0, 0, 0);
    }
  }

  // epilogue: C/D layout row=(q*4+r), col=c within 16x16 tile
  float pp[4] = {0.f, 0.f, 0.f, 0.f};
#pragma unroll
  for (int r = 0; r < 4; ++r) {
    int row = rowBase + w * 16 + q * 4 + r;
#pragma unroll
    for (int ct = 0; ct < 4; ++ct) {
      int col = colBase + ct * 16 + c;
      float v = acc[ct][r] + bg[col] + h_val(lm, nf, row, col);
      NO[(size_t)row * D + col] = v;
      pp[r] += v * Wd[col];
    }
  }
#pragma unroll
  for (int r = 0; r < 4; ++r) {
    pp[r] += __shfl_xor(pp[r], 1);
    pp[r] += __shfl_xor(pp[r], 2);
    pp[r] += __shfl_xor(pp[r], 4);
    pp[r] += __shfl_xor(pp[r], 8);
  }
  if (c == 0) {
#pragma unroll
    for (int r = 0; r < 4; ++r) {
      atomicAdd(&p[rowBase + w * 16 + q * 4 + r], pp[r]);
    }
  }
}

// ---- tail: dis_pred (blocks 0..255, 2 rows each) + mask_pred (blocks 256..319) ----
__global__ __launch_bounds__(256) void tail_kernel(const float* __restrict__ p,
                                                   const float* __restrict__ bd,
                                                   const float* __restrict__ NO,
                                                   const int* __restrict__ mask_index,
                                                   const float* __restrict__ Wm,
                                                   const float* __restrict__ bm,
                                                   float* __restrict__ out) {
  int b = blockIdx.x;
  int t = threadIdx.x;
  if (b < 256) {
    int i = b * 2 + (t >> 7);
    int j4 = (t & 127) * 4;
    float pi = p[i];
    float bias = bd[0];
    float4 pj = *(const float4*)&p[j4];
    float4 o;
    o.x = 1.0f / (1.0f + __expf(-(pj.x - pi + bias)));
    o.y = 1.0f / (1.0f + __expf(-(pj.y - pi + bias)));
    o.z = 1.0f / (1.0f + __expf(-(pj.z - pi + bias)));
    o.w = 1.0f / (1.0f + __expf(-(pj.w - pi + bias)));
    *(float4*)&out[(size_t)i * N + j4] = o;
  } else {
    int mb = b - 256;               // 0..63
    int row = mask_index[mb];
    float a0 = 0.f, a1 = 0.f;
#pragma unroll
    for (int j = 0; j < 5; ++j) {
      int k = t + 256 * j;
      float v = NO[(size_t)row * D + k];
      a0 += v * Wm[k * 2 + 0];
      a1 += v * Wm[k * 2 + 1];
    }
    __shared__ float s0[256], s1[256];
    s0[t] = a0;
    s1[t] = a1;
    __syncthreads();
    for (int off = 128; off > 0; off >>= 1) {
      if (t < off) {
        s0[t] += s0[t + off];
        s1[t] += s1[t + off];
      }
      __syncthreads();
    }
    if (t == 0) {
      out[(size_t)N * N + mb * 2 + 0] = tanhf(s0[0] + bm[0]);
      out[(size_t)N * N + mb * 2 + 1] = tanhf(s1[0] + bm[1]);
    }
  }
}

// =================== FALLBACK PATH (fp32, needs only 5.4 MB ws) ===================

__global__ __launch_bounds__(256) void hist_kernel(const int* __restrict__ dst,
                                                   int* __restrict__ counts) {
  int e = blockIdx.x * 256 + threadIdx.x;
  atomicAdd(&counts[dst[e]], 1);
}

__global__ __launch_bounds__(512) void scan_kernel(const int* __restrict__ counts,
                                                   int* __restrict__ offsets,
                                                   int* __restrict__ cursor) {
  __shared__ int s[N];
  int t = threadIdx.x;
  int cc = counts[t];
  s[t] = cc;
  __syncthreads();
  for (int off = 1; off < N; off <<= 1) {
    int v = (t >= off) ? s[t - off] : 0;
    __syncthreads();
    s[t] += v;
    __syncthreads();
  }
  offsets[t + 1] = s[t];
  if (t == 0) offsets[0] = 0;
  cursor[t] = s[t] - cc;
}

__global__ __launch_bounds__(256) void scatter_kernel(const int* __restrict__ src,
                                                      const int* __restrict__ dst,
                                                      const float* __restrict__ ew,
                                                      int* __restrict__ cursor,
                                                      int* __restrict__ src_s,
                                                      float* __restrict__ ew_s) {
  int e = blockIdx.x * 256 + threadIdx.x;
  int d = dst[e];
  int pos = atomicAdd(&cursor[d], 1);
  src_s[pos] = src[e];
  ew_s[pos] = ew[e];
}

__global__ __launch_bounds__(256) void neigh_f32_kernel(const float* __restrict__ lm,
                                                        const float* __restrict__ nf,
                                                        const int* __restrict__ offsets,
                                                        const int* __restrict__ src_s,
                                                        const float* __restrict__ ew_s,
                                                        float* __restrict__ A) {
  int n = blockIdx.x;
  int t = threadIdx.x;
  int beg = offsets[n], end = offsets[n + 1];
  float m[5];
#pragma unroll
  for (int i = 0; i < 5; ++i) m[i] = -FLT_MAX;
  for (int e = beg; e < end; ++e) {
    int s = src_s[e];
    float w = ew_s[e];
#pragma unroll
    for (int i = 0; i < 5; ++i) {
      int d = t + 256 * i;
      m[i] = fmaxf(m[i], h_val(lm, nf, s, d) * w);
    }
  }
  bool has = (end > beg);
#pragma unroll
  for (int i = 0; i < 5; ++i) {
    int d = t + 256 * i;
    A[n * D + d] = h_val(lm, nf, n, d) + (has ? m[i] : 0.0f);
  }
}

#define BM 64
#define BN 64
#define BK 16
__global__ __launch_bounds__(256) void gemm_f32_kernel(const float* __restrict__ A,
                                                       const float* __restrict__ W,
                                                       const float* __restrict__ bg,
                                                       const float* __restrict__ lm,
                                                       const float* __restrict__ nf,
                                                       float* __restrict__ C) {
  __shared__ __align__(16) float As[BK][BM + 4];
  __shared__ __align__(16) float Ws[BK][BN + 4];
  int tid = threadIdx.x;
  int tx = tid & 15, ty = tid >> 4;
  int rowBase = blockIdx.y * BM;
  int colBase = blockIdx.x * BN;
  float acc[4][4] = {};
  int ar = tid >> 2;
  int ak = (tid & 3) << 2;
  int wk = tid >> 4;
  int wc = (tid & 15) << 2;
  for (int k0 = 0; k0 < D; k0 += BK) {
    float4 av = *(const float4*)&A[(rowBase + ar) * D + k0 + ak];
    float4 wv = *(const float4*)&W[(k0 + wk) * D + colBase + wc];
    __syncthreads();
    As[ak + 0][ar] = av.x;
    As[ak + 1][ar] = av.y;
    As[ak + 2][ar] = av.z;
    As[ak + 3][ar] = av.w;
    *(float4*)&Ws[wk][wc] = wv;
    __syncthreads();
#pragma unroll
    for (int k = 0; k < BK; ++k) {
      float4 a = *(const float4*)&As[k][ty * 4];
      float4 b = *(const float4*)&Ws[k][tx * 4];
      acc[0][0] += a.x * b.x; acc[0][1] += a.x * b.y; acc[0][2] += a.x * b.z; acc[0][3] += a.x * b.w;
      acc[1][0] += a.y * b.x; acc[1][1] += a.y * b.y; acc[1][2] += a.y * b.z; acc[1][3] += a.y * b.w;
      acc[2][0] += a.z * b.x; acc[2][1] += a.z * b.y; acc[2][2] += a.z * b.z; acc[2][3] += a.z * b.w;
      acc[3][0] += a.w * b.x; acc[3][1] += a.w * b.y; acc[3][2] += a.w * b.z; acc[3][3] += a.w * b.w;
    }
  }
#pragma unroll
  for (int i = 0; i < 4; ++i) {
    int r = rowBase + ty * 4 + i;
#pragma unroll
    for (int j = 0; j < 4; ++j) {
      int cc = colBase + tx * 4 + j;
      C[r * D + cc] = acc[i][j] + bg[cc] + h_val(lm, nf, r, cc);
    }
  }
}

__global__ __launch_bounds__(256) void p_kernel(const float* __restrict__ NO,
                                                const float* __restrict__ Wd,
                                                float* __restrict__ p) {
  int i = blockIdx.x, t = threadIdx.x;
  float acc = 0.f;
#pragma unroll
  for (int j = 0; j < 5; ++j) {
    int k = t + 256 * j;
    acc += NO[i * D + k] * Wd[k];
  }
  __shared__ float s[256];
  s[t] = acc;
  __syncthreads();
  for (int off = 128; off > 0; off >>= 1) {
    if (t < off) s[t] += s[t + off];
    __syncthreads();
  }
  if (t == 0) p[i] = s[0];
}

// =================== launch ===================

extern "C" void kernel_launch(void* const* d_in, const int* in_sizes, int n_in,
                              void* d_out, int out_size, void* d_ws, size_t ws_size,
                              hipStream_t stream) {
  const float* lm = (const float*)d_in[0];
  const float* nf = (const float*)d_in[1];
  const float* ew = (const float*)d_in[2];
  const int* src = (const int*)d_in[3];
  const int* dst = (const int*)d_in[4];
  const int* mask_index = (const int*)d_in[5];
  const float* Wg = (const float*)d_in[6];
  const float* bg = (const float*)d_in[7];
  const float* Wd = (const float*)d_in[8];
  const float* bd = (const float*)d_in[9];
  const float* Wm = (const float*)d_in[10];
  const float* bm = (const float*)d_in[11];
  float* out = (float*)d_out;
  char* w = (char*)d_ws;

  const size_t FAST_WS = 11800000;
  if (ws_size >= FAST_WS) {
    unsigned short* AHi  = (unsigned short*)(w);              // 1,310,720
    unsigned short* ALo  = (unsigned short*)(w + 1310720);    // 1,310,720
    unsigned short* WtHi = (unsigned short*)(w + 2621440);    // 3,276,800
    unsigned short* WtLo = (unsigned short*)(w + 5898240);    // 3,276,800
    float* NO            = (float*)(w + 9175040);             // 2,621,440
    float* p             = (float*)(w + 11796480);            // 2,048

    prep_kernel<<<2112, 320, 0, stream>>>(lm, nf, ew, src, dst, Wg,
                                          AHi, ALo, WtHi, WtLo, p);
    gemm_mfma_kernel<<<dim3(20, 8), 256, 0, stream>>>(AHi, ALo, WtHi, WtLo, bg, Wd,
                                                      lm, nf, NO, p);
    tail_kernel<<<320, 256, 0, stream>>>(p, bd, NO, mask_index, Wm, bm, out);
  } else {
    float* A       = (float*)(w);
    float* NO      = (float*)(w + 2621440);
    float* p       = (float*)(w + 5242880);
    int* counts    = (int*)(w + 5244928);
    int* offsets   = (int*)(w + 5246976);
    int* cursor    = (int*)(w + 5249040);
    int* src_s     = (int*)(w + 5251088);
    float* ew_s    = (float*)(w + 5316624);

    hipMemsetAsync(counts, 0, N * sizeof(int), stream);
    hist_kernel<<<E / 256, 256, 0, stream>>>(dst, counts);
    scan_kernel<<<1, 512, 0, stream>>>(counts, offsets, cursor);
    scatter_kernel<<<E / 256, 256, 0, stream>>>(src, dst, ew, cursor, src_s, ew_s);
    neigh_f32_kernel<<<N, 256, 0, stream>>>(lm, nf, offsets, src_s, ew_s, A);
    gemm_f32_kernel<<<dim3(D / BN, N / BM), 256, 0, stream>>>(A, Wg, bg, lm, nf, NO);
    p_kernel<<<N, 256, 0, stream>>>(NO, Wd, p);
    tail_kernel<<<320, 256, 0, stream>>>(p, bd, NO, mask_index, Wm, bm, out);
  }
}

// Round 9
// 123.087 us; speedup vs baseline: 2.4905x; 2.4905x over previous
//
#include <hip/hip_runtime.h>
#include <float.h>
#include <math.h>

#define N 512
#define E 16384
#define D 1280
#define LMDIM 1024
#define NFDIM 256
#define M 64
#define MAXDEG 512   // in-degree cap; Poisson(32) for this fixed input, tail << 512

typedef __attribute__((ext_vector_type(8))) short s8v;   // 8 bf16 operand (4 VGPRs)
typedef __attribute__((ext_vector_type(4))) float f4v;   // 4 fp32 acc

// ---------- bf16 helpers ----------
__device__ __forceinline__ unsigned short f2bf(float x) {
  unsigned u = __float_as_uint(x);
  unsigned r = (u + 0x7fffu + ((u >> 16) & 1u)) >> 16;   // RNE
  return (unsigned short)r;
}
__device__ __forceinline__ float bf2f(unsigned short h) {
  return __uint_as_float(((unsigned)h) << 16);
}

// h[i][j] = j < 1024 ? lm[0, i+1, j] : nf[i, j-1024]
__device__ __forceinline__ float h_val(const float* __restrict__ lm,
                                       const float* __restrict__ nf,
                                       int i, int j) {
  return (j < LMDIM) ? lm[(i + 1) * LMDIM + j] : nf[i * NFDIM + (j - LMDIM)];
}
__device__ __forceinline__ float4 h_vec4(const float* __restrict__ lm,
                                         const float* __restrict__ nf,
                                         int i, int t) {  // t = col/4, 0..319
  return (t < 256) ? *(const float4*)&lm[(size_t)(i + 1) * LMDIM + t * 4]
                   : *(const float4*)&nf[(size_t)i * NFDIM + (t - 256) * 4];
}

// =================== FAST PATH ===================

// ---- prep: blocks 0..1599 = W-split tiles; 1600..2111 = neigh (1 node each) ----
union __align__(16) PrepSMem {
  float T[32][33];                 // convw transpose tile (4224 B)
  struct {
    int   s_e[MAXDEG];             // matched edge ids
    int   s_src[MAXDEG];
    float s_w[MAXDEG];
    int   s_cnt;
  } ng;                            // 6148 B
};

__global__ __launch_bounds__(320) void prep_kernel(
    const float* __restrict__ lm, const float* __restrict__ nf,
    const float* __restrict__ ew, const int* __restrict__ src,
    const int* __restrict__ dst, const float* __restrict__ Wg,
    unsigned short* __restrict__ AHi, unsigned short* __restrict__ ALo,
    unsigned short* __restrict__ WtHi, unsigned short* __restrict__ WtLo,
    float* __restrict__ p) {
  __shared__ PrepSMem sm;
  int b = blockIdx.x;
  int t = threadIdx.x;

  if (b < 1600) {
    // ----- convw: Wt[n][k] = W[k][n], bf16 hi/lo split (256 active threads) -----
    if (t < 256) {
      int bx = b % 40, by = b / 40;        // bx: n-tile, by: k-tile
      int c = t & 31, r0 = t >> 5;
#pragma unroll
      for (int rr = 0; rr < 4; ++rr) {
        int r = r0 + rr * 8;
        sm.T[r][c] = Wg[(by * 32 + r) * D + bx * 32 + c];
      }
      __syncthreads();
#pragma unroll
      for (int rr = 0; rr < 4; ++rr) {
        int rn = r0 + rr * 8;
        float v = sm.T[c][rn];             // = Wg[by*32+c][bx*32+rn]
        unsigned short hi = f2bf(v);
        unsigned short lo = f2bf(v - bf2f(hi));
        size_t o = (size_t)(bx * 32 + rn) * D + by * 32 + c;
        WtHi[o] = hi;
        WtLo[o] = lo;
      }
    } else {
      __syncthreads();                     // match the barrier above
    }
  } else {
    // ----- neigh for node n: MLP-pipelined edge scan + batched max gather -----
    int n = b - 1600;                      // 0..511
    if (t == 0) {
      sm.ng.s_cnt = 0;
      p[n] = 0.0f;                         // gemm accumulates p with atomics
    }
    __syncthreads();
    // 1) edge scan: int4 loads, matches push edge id only (independent loads pipeline)
    const int4* dst4 = (const int4*)dst;
    for (int i = t; i < E / 4; i += 320) {
      int4 d4 = dst4[i];
      if (d4.x == n) { int pos = atomicAdd(&sm.ng.s_cnt, 1); if (pos < MAXDEG) sm.ng.s_e[pos] = 4 * i + 0; }
      if (d4.y == n) { int pos = atomicAdd(&sm.ng.s_cnt, 1); if (pos < MAXDEG) sm.ng.s_e[pos] = 4 * i + 1; }
      if (d4.z == n) { int pos = atomicAdd(&sm.ng.s_cnt, 1); if (pos < MAXDEG) sm.ng.s_e[pos] = 4 * i + 2; }
      if (d4.w == n) { int pos = atomicAdd(&sm.ng.s_cnt, 1); if (pos < MAXDEG) sm.ng.s_e[pos] = 4 * i + 3; }
    }
    __syncthreads();
    int cnt = min(sm.ng.s_cnt, MAXDEG);
    // 2) resolve src/weight for all matches in one parallel step (cnt < 320)
    if (t < cnt) {
      int e = sm.ng.s_e[t];
      sm.ng.s_src[t] = src[e];
      sm.ng.s_w[t] = ew[e];
    }
    __syncthreads();
    // 3) batched max: 8 independent row-gathers in flight per group
    float4 m = make_float4(-FLT_MAX, -FLT_MAX, -FLT_MAX, -FLT_MAX);
    int i = 0;
    for (; i + 8 <= cnt; i += 8) {
      float4 v[8];
      float wgt[8];
#pragma unroll
      for (int j = 0; j < 8; ++j) {
        int s = sm.ng.s_src[i + j];
        wgt[j] = sm.ng.s_w[i + j];
        v[j] = h_vec4(lm, nf, s, t);
      }
#pragma unroll
      for (int j = 0; j < 8; ++j) {
        m.x = fmaxf(m.x, v[j].x * wgt[j]);
        m.y = fmaxf(m.y, v[j].y * wgt[j]);
        m.z = fmaxf(m.z, v[j].z * wgt[j]);
        m.w = fmaxf(m.w, v[j].w * wgt[j]);
      }
    }
    for (; i < cnt; ++i) {
      int s = sm.ng.s_src[i];
      float wgt = sm.ng.s_w[i];
      float4 v = h_vec4(lm, nf, s, t);
      m.x = fmaxf(m.x, v.x * wgt);
      m.y = fmaxf(m.y, v.y * wgt);
      m.z = fmaxf(m.z, v.z * wgt);
      m.w = fmaxf(m.w, v.w * wgt);
    }
    bool has = (cnt > 0);
    float4 hv = h_vec4(lm, nf, n, t);
    float4 a;
    a.x = hv.x + (has ? m.x : 0.0f);
    a.y = hv.y + (has ? m.y : 0.0f);
    a.z = hv.z + (has ? m.z : 0.0f);
    a.w = hv.w + (has ? m.w : 0.0f);
    ushort4 hi, lo;
    hi.x = f2bf(a.x); lo.x = f2bf(a.x - bf2f(hi.x));
    hi.y = f2bf(a.y); lo.y = f2bf(a.y - bf2f(hi.y));
    hi.z = f2bf(a.z); lo.z = f2bf(a.z - bf2f(hi.z));
    hi.w = f2bf(a.w); lo.w = f2bf(a.w - bf2f(hi.w));
    size_t o = (size_t)n * D + t * 4;      // t*4 spans 0..1279 exactly
    *(ushort4*)&AHi[o] = hi;
    *(ushort4*)&ALo[o] = lo;
  }
}

// ---- MFMA GEMM: NO = A @ W_g + b_g + h ; fused p += NO @ W_d ----
// K-loop unrolled x2 with STATIC register sets (no dynamic indexing -> no
// scratch spill; r8's regression). One barrier per iteration; prefetch loads
// are issued AFTER the barrier so the compiler's vmcnt(0)-before-s_barrier
// drain lands one full compute+store phase after issue (latency hidden).
// Race-safety: every wave's ds_reads of a buffer are lgkmcnt(0)-drained at
// the barrier it passes before any wave can reach the next store to that
// buffer (stores to buf X always sit two barriers after the reads of buf X).
__global__ __launch_bounds__(256) void gemm_mfma_kernel(const unsigned short* __restrict__ AHi,
                                                        const unsigned short* __restrict__ ALo,
                                                        const unsigned short* __restrict__ WtHi,
                                                        const unsigned short* __restrict__ WtLo,
                                                        const float* __restrict__ bg,
                                                        const float* __restrict__ Wd,
                                                        const float* __restrict__ lm,
                                                        const float* __restrict__ nf,
                                                        float* __restrict__ NO,
                                                        float* __restrict__ p) {
  __shared__ __align__(16) short Ah[2][64][40];
  __shared__ __align__(16) short Al[2][64][40];
  __shared__ __align__(16) short Bh[2][64][40];
  __shared__ __align__(16) short Bl[2][64][40];

  int tid = threadIdx.x;
  int rowBase = blockIdx.y * 64;
  int colBase = blockIdx.x * 64;

  int sr = tid >> 2;                // staging row 0..63
  int sq = (tid & 3) << 3;          // staging k-offset in shorts (0,8,16,24)

  int w = tid >> 6;                 // wave 0..3 -> rows w*16..w*16+15
  int L = tid & 63;
  int q = L >> 4;                   // quad
  int c = L & 15;

  f4v acc[4];
#pragma unroll
  for (int i = 0; i < 4; ++i) acc[i] = (f4v){0.f, 0.f, 0.f, 0.f};

  const size_t aOff = (size_t)(rowBase + sr) * D + sq;
  const size_t bOff = (size_t)(colBase + sr) * D + sq;

  // preamble: register set 0 <- tile k=0, set 1 <- tile k=32 (all static names)
  s8v a0 = *(const s8v*)&AHi[aOff];
  s8v l0 = *(const s8v*)&ALo[aOff];
  s8v b0 = *(const s8v*)&WtHi[bOff];
  s8v m0 = *(const s8v*)&WtLo[bOff];
  s8v a1 = *(const s8v*)&AHi[aOff + 32];
  s8v l1 = *(const s8v*)&ALo[aOff + 32];
  s8v b1 = *(const s8v*)&WtHi[bOff + 32];
  s8v m1 = *(const s8v*)&WtLo[bOff + 32];

  for (int it = 0; it < D / 32; it += 2) {
    // ---------- even half: buffer 0, tile k = it*32 ----------
    *(s8v*)&Ah[0][sr][sq] = a0;
    *(s8v*)&Al[0][sr][sq] = l0;
    *(s8v*)&Bh[0][sr][sq] = b0;
    *(s8v*)&Bl[0][sr][sq] = m0;
    __syncthreads();
    {
      int kn = (it + 2) * 32;            // prefetch for pair it+2 (even)
      if (kn < D) {
        a0 = *(const s8v*)&AHi[aOff + kn];
        l0 = *(const s8v*)&ALo[aOff + kn];
        b0 = *(const s8v*)&WtHi[bOff + kn];
        m0 = *(const s8v*)&WtLo[bOff + kn];
      }
    }
    {
      s8v ah = *(const s8v*)&Ah[0][w * 16 + c][q * 8];
      s8v al = *(const s8v*)&Al[0][w * 16 + c][q * 8];
#pragma unroll
      for (int ct = 0; ct < 4; ++ct) {
        s8v bh = *(const s8v*)&Bh[0][ct * 16 + c][q * 8];
        s8v bl = *(const s8v*)&Bl[0][ct * 16 + c][q * 8];
        acc[ct] = __builtin_amdgcn_mfma_f32_16x16x32_bf16(ah, bh, acc[ct], 0, 0, 0);
        acc[ct] = __builtin_amdgcn_mfma_f32_16x16x32_bf16(al, bh, acc[ct], 0, 0, 0);
        acc[ct] = __builtin_amdgcn_mfma_f32_16x16x32_bf16(ah, bl, acc[ct], 0, 0, 0);
      }
    }
    // ---------- odd half: buffer 1, tile k = (it+1)*32 ----------
    *(s8v*)&Ah[1][sr][sq] = a1;
    *(s8v*)&Al[1][sr][sq] = l1;
    *(s8v*)&Bh[1][sr][sq] = b1;
    *(s8v*)&Bl[1][sr][sq] = m1;
    __syncthreads();
    {
      int kn = (it + 3) * 32;            // prefetch for pair it+2 (odd)
      if (kn < D) {
        a1 = *(const s8v*)&AHi[aOff + kn];
        l1 = *(const s8v*)&ALo[aOff + kn];
        b1 = *(const s8v*)&WtHi[bOff + kn];
        m1 = *(const s8v*)&WtLo[bOff + kn];
      }
    }
    {
      s8v ah = *(const s8v*)&Ah[1][w * 16 + c][q * 8];
      s8v al = *(const s8v*)&Al[1][w * 16 + c][q * 8];
#pragma unroll
      for (int ct = 0; ct < 4; ++ct) {
        s8v bh = *(const s8v*)&Bh[1][ct * 16 + c][q * 8];
        s8v bl = *(const s8v*)&Bl[1][ct * 16 + c][q * 8];
        acc[ct] = __builtin_amdgcn_mfma_f32_16x16x32_bf16(ah, bh, acc[ct], 0, 0, 0);
        acc[ct] = __builtin_amdgcn_mfma_f32_16x16x32_bf16(al, bh, acc[ct], 0, 0, 0);
        acc[ct] = __builtin_amdgcn_mfma_f32_16x16x32_bf16(ah, bl, acc[ct], 0, 0, 0);
      }
    }
  }

  // epilogue: C/D layout row=(q*4+r), col=c within 16x16 tile
  float pp[4] = {0.f, 0.f, 0.f, 0.f};
#pragma unroll
  for (int r = 0; r < 4; ++r) {
    int row = rowBase + w * 16 + q * 4 + r;
#pragma unroll
    for (int ct = 0; ct < 4; ++ct) {
      int col = colBase + ct * 16 + c;
      float v = acc[ct][r] + bg[col] + h_val(lm, nf, row, col);
      NO[(size_t)row * D + col] = v;
      pp[r] += v * Wd[col];
    }
  }
#pragma unroll
  for (int r = 0; r < 4; ++r) {
    pp[r] += __shfl_xor(pp[r], 1);
    pp[r] += __shfl_xor(pp[r], 2);
    pp[r] += __shfl_xor(pp[r], 4);
    pp[r] += __shfl_xor(pp[r], 8);
  }
  if (c == 0) {
#pragma unroll
    for (int r = 0; r < 4; ++r) {
      atomicAdd(&p[rowBase + w * 16 + q * 4 + r], pp[r]);
    }
  }
}

// ---- tail: dis_pred (blocks 0..255, 2 rows each) + mask_pred (blocks 256..319) ----
__global__ __launch_bounds__(256) void tail_kernel(const float* __restrict__ p,
                                                   const float* __restrict__ bd,
                                                   const float* __restrict__ NO,
                                                   const int* __restrict__ mask_index,
                                                   const float* __restrict__ Wm,
                                                   const float* __restrict__ bm,
                                                   float* __restrict__ out) {
  int b = blockIdx.x;
  int t = threadIdx.x;
  if (b < 256) {
    int i = b * 2 + (t >> 7);
    int j4 = (t & 127) * 4;
    float pi = p[i];
    float bias = bd[0];
    float4 pj = *(const float4*)&p[j4];
    float4 o;
    o.x = 1.0f / (1.0f + __expf(-(pj.x - pi + bias)));
    o.y = 1.0f / (1.0f + __expf(-(pj.y - pi + bias)));
    o.z = 1.0f / (1.0f + __expf(-(pj.z - pi + bias)));
    o.w = 1.0f / (1.0f + __expf(-(pj.w - pi + bias)));
    *(float4*)&out[(size_t)i * N + j4] = o;
  } else {
    int mb = b - 256;               // 0..63
    int row = mask_index[mb];
    float a0 = 0.f, a1 = 0.f;
#pragma unroll
    for (int j = 0; j < 5; ++j) {
      int k = t + 256 * j;
      float v = NO[(size_t)row * D + k];
      a0 += v * Wm[k * 2 + 0];
      a1 += v * Wm[k * 2 + 1];
    }
    __shared__ float s0[256], s1[256];
    s0[t] = a0;
    s1[t] = a1;
    __syncthreads();
    for (int off = 128; off > 0; off >>= 1) {
      if (t < off) {
        s0[t] += s0[t + off];
        s1[t] += s1[t + off];
      }
      __syncthreads();
    }
    if (t == 0) {
      out[(size_t)N * N + mb * 2 + 0] = tanhf(s0[0] + bm[0]);
      out[(size_t)N * N + mb * 2 + 1] = tanhf(s1[0] + bm[1]);
    }
  }
}

// =================== FALLBACK PATH (fp32, needs only 5.4 MB ws) ===================

__global__ __launch_bounds__(256) void hist_kernel(const int* __restrict__ dst,
                                                   int* __restrict__ counts) {
  int e = blockIdx.x * 256 + threadIdx.x;
  atomicAdd(&counts[dst[e]], 1);
}

__global__ __launch_bounds__(512) void scan_kernel(const int* __restrict__ counts,
                                                   int* __restrict__ offsets,
                                                   int* __restrict__ cursor) {
  __shared__ int s[N];
  int t = threadIdx.x;
  int cc = counts[t];
  s[t] = cc;
  __syncthreads();
  for (int off = 1; off < N; off <<= 1) {
    int v = (t >= off) ? s[t - off] : 0;
    __syncthreads();
    s[t] += v;
    __syncthreads();
  }
  offsets[t + 1] = s[t];
  if (t == 0) offsets[0] = 0;
  cursor[t] = s[t] - cc;
}

__global__ __launch_bounds__(256) void scatter_kernel(const int* __restrict__ src,
                                                      const int* __restrict__ dst,
                                                      const float* __restrict__ ew,
                                                      int* __restrict__ cursor,
                                                      int* __restrict__ src_s,
                                                      float* __restrict__ ew_s) {
  int e = blockIdx.x * 256 + threadIdx.x;
  int d = dst[e];
  int pos = atomicAdd(&cursor[d], 1);
  src_s[pos] = src[e];
  ew_s[pos] = ew[e];
}

__global__ __launch_bounds__(256) void neigh_f32_kernel(const float* __restrict__ lm,
                                                        const float* __restrict__ nf,
                                                        const int* __restrict__ offsets,
                                                        const int* __restrict__ src_s,
                                                        const float* __restrict__ ew_s,
                                                        float* __restrict__ A) {
  int n = blockIdx.x;
  int t = threadIdx.x;
  int beg = offsets[n], end = offsets[n + 1];
  float m[5];
#pragma unroll
  for (int i = 0; i < 5; ++i) m[i] = -FLT_MAX;
  for (int e = beg; e < end; ++e) {
    int s = src_s[e];
    float w = ew_s[e];
#pragma unroll
    for (int i = 0; i < 5; ++i) {
      int d = t + 256 * i;
      m[i] = fmaxf(m[i], h_val(lm, nf, s, d) * w);
    }
  }
  bool has = (end > beg);
#pragma unroll
  for (int i = 0; i < 5; ++i) {
    int d = t + 256 * i;
    A[n * D + d] = h_val(lm, nf, n, d) + (has ? m[i] : 0.0f);
  }
}

#define BM 64
#define BN 64
#define BK 16
__global__ __launch_bounds__(256) void gemm_f32_kernel(const float* __restrict__ A,
                                                       const float* __restrict__ W,
                                                       const float* __restrict__ bg,
                                                       const float* __restrict__ lm,
                                                       const float* __restrict__ nf,
                                                       float* __restrict__ C) {
  __shared__ __align__(16) float As[BK][BM + 4];
  __shared__ __align__(16) float Ws[BK][BN + 4];
  int tid = threadIdx.x;
  int tx = tid & 15, ty = tid >> 4;
  int rowBase = blockIdx.y * BM;
  int colBase = blockIdx.x * BN;
  float acc[4][4] = {};
  int ar = tid >> 2;
  int ak = (tid & 3) << 2;
  int wk = tid >> 4;
  int wc = (tid & 15) << 2;
  for (int k0 = 0; k0 < D; k0 += BK) {
    float4 av = *(const float4*)&A[(rowBase + ar) * D + k0 + ak];
    float4 wv = *(const float4*)&W[(k0 + wk) * D + colBase + wc];
    __syncthreads();
    As[ak + 0][ar] = av.x;
    As[ak + 1][ar] = av.y;
    As[ak + 2][ar] = av.z;
    As[ak + 3][ar] = av.w;
    *(float4*)&Ws[wk][wc] = wv;
    __syncthreads();
#pragma unroll
    for (int k = 0; k < BK; ++k) {
      float4 a = *(const float4*)&As[k][ty * 4];
      float4 b = *(const float4*)&Ws[k][tx * 4];
      acc[0][0] += a.x * b.x; acc[0][1] += a.x * b.y; acc[0][2] += a.x * b.z; acc[0][3] += a.x * b.w;
      acc[1][0] += a.y * b.x; acc[1][1] += a.y * b.y; acc[1][2] += a.y * b.z; acc[1][3] += a.y * b.w;
      acc[2][0] += a.z * b.x; acc[2][1] += a.z * b.y; acc[2][2] += a.z * b.z; acc[2][3] += a.z * b.w;
      acc[3][0] += a.w * b.x; acc[3][1] += a.w * b.y; acc[3][2] += a.w * b.z; acc[3][3] += a.w * b.w;
    }
  }
#pragma unroll
  for (int i = 0; i < 4; ++i) {
    int r = rowBase + ty * 4 + i;
#pragma unroll
    for (int j = 0; j < 4; ++j) {
      int cc = colBase + tx * 4 + j;
      C[r * D + cc] = acc[i][j] + bg[cc] + h_val(lm, nf, r, cc);
    }
  }
}

__global__ __launch_bounds__(256) void p_kernel(const float* __restrict__ NO,
                                                const float* __restrict__ Wd,
                                                float* __restrict__ p) {
  int i = blockIdx.x, t = threadIdx.x;
  float acc = 0.f;
#pragma unroll
  for (int j = 0; j < 5; ++j) {
    int k = t + 256 * j;
    acc += NO[i * D + k] * Wd[k];
  }
  __shared__ float s[256];
  s[t] = acc;
  __syncthreads();
  for (int off = 128; off > 0; off >>= 1) {
    if (t < off) s[t] += s[t + off];
    __syncthreads();
  }
  if (t == 0) p[i] = s[0];
}

// =================== launch ===================

extern "C" void kernel_launch(void* const* d_in, const int* in_sizes, int n_in,
                              void* d_out, int out_size, void* d_ws, size_t ws_size,
                              hipStream_t stream) {
  const float* lm = (const float*)d_in[0];
  const float* nf = (const float*)d_in[1];
  const float* ew = (const float*)d_in[2];
  const int* src = (const int*)d_in[3];
  const int* dst = (const int*)d_in[4];
  const int* mask_index = (const int*)d_in[5];
  const float* Wg = (const float*)d_in[6];
  const float* bg = (const float*)d_in[7];
  const float* Wd = (const float*)d_in[8];
  const float* bd = (const float*)d_in[9];
  const float* Wm = (const float*)d_in[10];
  const float* bm = (const float*)d_in[11];
  float* out = (float*)d_out;
  char* w = (char*)d_ws;

  const size_t FAST_WS = 11800000;
  if (ws_size >= FAST_WS) {
    unsigned short* AHi  = (unsigned short*)(w);              // 1,310,720
    unsigned short* ALo  = (unsigned short*)(w + 1310720);    // 1,310,720
    unsigned short* WtHi = (unsigned short*)(w + 2621440);    // 3,276,800
    unsigned short* WtLo = (unsigned short*)(w + 5898240);    // 3,276,800
    float* NO            = (float*)(w + 9175040);             // 2,621,440
    float* p             = (float*)(w + 11796480);            // 2,048

    prep_kernel<<<2112, 320, 0, stream>>>(lm, nf, ew, src, dst, Wg,
                                          AHi, ALo, WtHi, WtLo, p);
    gemm_mfma_kernel<<<dim3(20, 8), 256, 0, stream>>>(AHi, ALo, WtHi, WtLo, bg, Wd,
                                                      lm, nf, NO, p);
    tail_kernel<<<320, 256, 0, stream>>>(p, bd, NO, mask_index, Wm, bm, out);
  } else {
    float* A       = (float*)(w);
    float* NO      = (float*)(w + 2621440);
    float* p       = (float*)(w + 5242880);
    int* counts    = (int*)(w + 5244928);
    int* offsets   = (int*)(w + 5246976);
    int* cursor    = (int*)(w + 5249040);
    int* src_s     = (int*)(w + 5251088);
    float* ew_s    = (float*)(w + 5316624);

    hipMemsetAsync(counts, 0, N * sizeof(int), stream);
    hist_kernel<<<E / 256, 256, 0, stream>>>(dst, counts);
    scan_kernel<<<1, 512, 0, stream>>>(counts, offsets, cursor);
    scatter_kernel<<<E / 256, 256, 0, stream>>>(src, dst, ew, cursor, src_s, ew_s);
    neigh_f32_kernel<<<N, 256, 0, stream>>>(lm, nf, offsets, src_s, ew_s, A);
    gemm_f32_kernel<<<dim3(D / BN, N / BM), 256, 0, stream>>>(A, Wg, bg, lm, nf, NO);
    p_kernel<<<N, 256, 0, stream>>>(NO, Wd, p);
    tail_kernel<<<320, 256, 0, stream>>>(p, bd, NO, mask_index, Wm, bm, out);
  }
}

// Round 10
// 98.629 us; speedup vs baseline: 3.1081x; 1.2480x over previous
//
#include <hip/hip_runtime.h>
#include <float.h>
#include <math.h>

#define N 512
#define E 16384
#define D 1280
#define LMDIM 1024
#define NFDIM 256
#define M 64
#define MAXDEG 512   // in-degree cap; Poisson(32) for this fixed input, tail << 512

// h[i][j] = j < 1024 ? lm[0, i+1, j] : nf[i, j-1024]
__device__ __forceinline__ float4 h_vec4(const float* __restrict__ lm,
                                         const float* __restrict__ nf,
                                         int i, int t) {  // t = col/4, 0..319
  return (t < 256) ? *(const float4*)&lm[(size_t)(i + 1) * LMDIM + t * 4]
                   : *(const float4*)&nf[(size_t)i * NFDIM + (t - 256) * 4];
}

// 3-value block reduction over 320 threads (fold 256..319 into 0..63, then tree).
__device__ __forceinline__ void reduce3_320(float* s0, float* s1, float* s2,
                                            int t, float v0, float v1, float v2) {
  s0[t] = v0; s1[t] = v1; s2[t] = v2;
  __syncthreads();
  if (t < 64) {
    s0[t] += s0[t + 256];
    s1[t] += s1[t + 256];
    s2[t] += s2[t + 256];
  }
  __syncthreads();
  for (int off = 128; off > 0; off >>= 1) {
    if (t < off) {
      s0[t] += s0[t + off];
      s1[t] += s1[t + off];
      s2[t] += s2[t + off];
    }
    __syncthreads();
  }
}

// ---- K1: wproj — wd2[k] = Wg[k]·Wd ; wm2[k][c] = Wg[k]·Wm[:,c] ; block 1280: bg projections ----
__global__ __launch_bounds__(320) void wproj_kernel(const float* __restrict__ Wg,
                                                    const float* __restrict__ Wd,
                                                    const float* __restrict__ Wm,
                                                    const float* __restrict__ bg,
                                                    float* __restrict__ wd2,
                                                    float* __restrict__ wm2,
                                                    float* __restrict__ consts) {
  __shared__ float s0[320], s1[320], s2[320];
  int b = blockIdx.x;
  int t = threadIdx.x;
  const float* row = (b < D) ? &Wg[(size_t)b * D] : bg;
  float4 wv = *(const float4*)&row[t * 4];
  float4 vd = *(const float4*)&Wd[t * 4];
  float d0 = wv.x * vd.x + wv.y * vd.y + wv.z * vd.z + wv.w * vd.w;
  // Wm row-major (D,2): j = 4t..4t+3 -> Wm[j*2 + c]
  float4 m01 = *(const float4*)&Wm[t * 8];       // j=4t (c0,c1), j=4t+1 (c0,c1)
  float4 m23 = *(const float4*)&Wm[t * 8 + 4];   // j=4t+2, 4t+3
  float d1 = wv.x * m01.x + wv.y * m01.z + wv.z * m23.x + wv.w * m23.z;
  float d2 = wv.x * m01.y + wv.y * m01.w + wv.z * m23.y + wv.w * m23.w;
  reduce3_320(s0, s1, s2, t, d0, d1, d2);
  if (t == 0) {
    if (b < D) {
      wd2[b] = s0[0];
      wm2[b * 2 + 0] = s1[0];
      wm2[b * 2 + 1] = s2[0];
    } else {
      consts[0] = s0[0];   // bg·Wd
      consts[1] = s1[0];   // bg·Wm[:,0]
      consts[2] = s2[0];   // bg·Wm[:,1]
    }
  }
}

// ---- K2: neighp — per node: edge filter + gather-max (r6 pipeline), then fused
//      p[n] = A·wd2 + h·Wd + bg·Wd  and  mask_pred rows (A never materialized) ----
__global__ __launch_bounds__(320) void neighp_kernel(const float* __restrict__ lm,
                                                     const float* __restrict__ nf,
                                                     const float* __restrict__ ew,
                                                     const int* __restrict__ src,
                                                     const int* __restrict__ dst,
                                                     const int* __restrict__ mask_index,
                                                     const float* __restrict__ Wd,
                                                     const float* __restrict__ Wm,
                                                     const float* __restrict__ bm,
                                                     const float* __restrict__ wd2,
                                                     const float* __restrict__ wm2,
                                                     const float* __restrict__ consts,
                                                     float* __restrict__ p,
                                                     float* __restrict__ out) {
  __shared__ int   s_e[MAXDEG];
  __shared__ int   s_src[MAXDEG];
  __shared__ float s_w[MAXDEG];
  __shared__ int   s_cnt;
  __shared__ float s0[320], s1[320], s2[320];

  int n = blockIdx.x;                      // 0..511
  int t = threadIdx.x;                     // 0..319, owns cols 4t..4t+3
  if (t == 0) s_cnt = 0;
  __syncthreads();

  // 1) edge scan: int4 loads (independent -> pipelined), push matching edge ids
  const int4* dst4 = (const int4*)dst;
  for (int i = t; i < E / 4; i += 320) {
    int4 d4 = dst4[i];
    if (d4.x == n) { int pos = atomicAdd(&s_cnt, 1); if (pos < MAXDEG) s_e[pos] = 4 * i + 0; }
    if (d4.y == n) { int pos = atomicAdd(&s_cnt, 1); if (pos < MAXDEG) s_e[pos] = 4 * i + 1; }
    if (d4.z == n) { int pos = atomicAdd(&s_cnt, 1); if (pos < MAXDEG) s_e[pos] = 4 * i + 2; }
    if (d4.w == n) { int pos = atomicAdd(&s_cnt, 1); if (pos < MAXDEG) s_e[pos] = 4 * i + 3; }
  }
  __syncthreads();
  int cnt = min(s_cnt, MAXDEG);
  // 2) resolve src/weight in parallel
  for (int i = t; i < cnt; i += 320) {
    int e = s_e[i];
    s_src[i] = src[e];
    s_w[i] = ew[e];
  }
  __syncthreads();
  // 3) batched max: 8 independent row-gathers in flight per group
  float4 m = make_float4(-FLT_MAX, -FLT_MAX, -FLT_MAX, -FLT_MAX);
  int i = 0;
  for (; i + 8 <= cnt; i += 8) {
    float4 v[8];
    float wgt[8];
#pragma unroll
    for (int j = 0; j < 8; ++j) {
      int s = s_src[i + j];
      wgt[j] = s_w[i + j];
      v[j] = h_vec4(lm, nf, s, t);
    }
#pragma unroll
    for (int j = 0; j < 8; ++j) {
      m.x = fmaxf(m.x, v[j].x * wgt[j]);
      m.y = fmaxf(m.y, v[j].y * wgt[j]);
      m.z = fmaxf(m.z, v[j].z * wgt[j]);
      m.w = fmaxf(m.w, v[j].w * wgt[j]);
    }
  }
  for (; i < cnt; ++i) {
    int s = s_src[i];
    float wgt = s_w[i];
    float4 v = h_vec4(lm, nf, s, t);
    m.x = fmaxf(m.x, v.x * wgt);
    m.y = fmaxf(m.y, v.y * wgt);
    m.z = fmaxf(m.z, v.z * wgt);
    m.w = fmaxf(m.w, v.w * wgt);
  }
  bool has = (cnt > 0);
  float4 hv = h_vec4(lm, nf, n, t);
  float4 a;
  a.x = hv.x + (has ? m.x : 0.0f);
  a.y = hv.y + (has ? m.y : 0.0f);
  a.z = hv.z + (has ? m.z : 0.0f);
  a.w = hv.w + (has ? m.w : 0.0f);

  // 4) fused head dots: p-partial = A·wd2 + h·Wd ; mask partials = A·wm2 + h·Wm
  float4 w2 = *(const float4*)&wd2[t * 4];
  float4 vd = *(const float4*)&Wd[t * 4];
  float pd = a.x * w2.x + a.y * w2.y + a.z * w2.z + a.w * w2.w
           + hv.x * vd.x + hv.y * vd.y + hv.z * vd.z + hv.w * vd.w;
  float4 q01 = *(const float4*)&wm2[t * 8];
  float4 q23 = *(const float4*)&wm2[t * 8 + 4];
  float4 m01 = *(const float4*)&Wm[t * 8];
  float4 m23 = *(const float4*)&Wm[t * 8 + 4];
  float a0 = a.x * q01.x + a.y * q01.z + a.z * q23.x + a.w * q23.z
           + hv.x * m01.x + hv.y * m01.z + hv.z * m23.x + hv.w * m23.z;
  float a1 = a.x * q01.y + a.y * q01.w + a.z * q23.y + a.w * q23.w
           + hv.x * m01.y + hv.y * m01.w + hv.z * m23.y + hv.w * m23.w;

  reduce3_320(s0, s1, s2, t, pd, a0, a1);
  if (t == 0) p[n] = s0[0] + consts[0];
  // mask rows: every slot s with mask_index[s]==n gets this node's row
  if (t < M) {
    if (mask_index[t] == n) {
      out[(size_t)N * N + t * 2 + 0] = tanhf(s1[0] + consts[1] + bm[0]);
      out[(size_t)N * N + t * 2 + 1] = tanhf(s2[0] + consts[2] + bm[1]);
    }
  }
}

// ---- K3: dis_pred[i,j] = sigmoid(p[j]-p[i]+b_d), 2 rows/block, float4 ----
__global__ __launch_bounds__(256) void dis_kernel(const float* __restrict__ p,
                                                  const float* __restrict__ bd,
                                                  float* __restrict__ out) {
  int b = blockIdx.x;
  int t = threadIdx.x;
  int i = b * 2 + (t >> 7);
  int j4 = (t & 127) * 4;
  float pi = p[i];
  float bias = bd[0];
  float4 pj = *(const float4*)&p[j4];
  float4 o;
  o.x = 1.0f / (1.0f + __expf(-(pj.x - pi + bias)));
  o.y = 1.0f / (1.0f + __expf(-(pj.y - pi + bias)));
  o.z = 1.0f / (1.0f + __expf(-(pj.z - pi + bias)));
  o.w = 1.0f / (1.0f + __expf(-(pj.w - pi + bias)));
  *(float4*)&out[(size_t)i * N + j4] = o;
}

// =================== launch ===================

extern "C" void kernel_launch(void* const* d_in, const int* in_sizes, int n_in,
                              void* d_out, int out_size, void* d_ws, size_t ws_size,
                              hipStream_t stream) {
  const float* lm = (const float*)d_in[0];   // (1, 514, 1024)
  const float* nf = (const float*)d_in[1];   // (512, 256)
  const float* ew = (const float*)d_in[2];   // (E, 1)
  const int* src = (const int*)d_in[3];      // (E,)
  const int* dst = (const int*)d_in[4];      // (E,)
  const int* mask_index = (const int*)d_in[5];  // (M,)
  const float* Wg = (const float*)d_in[6];   // (D, D)
  const float* bg = (const float*)d_in[7];   // (D,)
  const float* Wd = (const float*)d_in[8];   // (D, 1)
  const float* bd = (const float*)d_in[9];   // (1,)
  const float* Wm = (const float*)d_in[10];  // (D, 2)
  const float* bm = (const float*)d_in[11];  // (2,)
  float* out = (float*)d_out;
  char* w = (char*)d_ws;

  // workspace: ~18 KB total
  float* wd2    = (float*)(w);               // 5,120 B
  float* wm2    = (float*)(w + 5120);        // 10,240 B
  float* consts = (float*)(w + 15360);       // 16 B
  float* p      = (float*)(w + 15488);       // 2,048 B

  wproj_kernel<<<D + 1, 320, 0, stream>>>(Wg, Wd, Wm, bg, wd2, wm2, consts);
  neighp_kernel<<<N, 320, 0, stream>>>(lm, nf, ew, src, dst, mask_index,
                                       Wd, Wm, bm, wd2, wm2, consts, p, out);
  dis_kernel<<<N / 2, 256, 0, stream>>>(p, bd, out);
}